// Round 15
// baseline (150.838 us; speedup 1.0000x reference)
//
#include <hip/hip_runtime.h>
#include <cstdint>
#include <cstddef>

#define B_     128
#define N_TOK  196
#define D_IN   768
#define K_SEL  144
#define P_     2000
#define PPAD   2048
#define C_     192
#define NC_    200
#define RPB    145            // rows per batch: 1 cls + 144 selected (no pad)
#define M_PAD  (B_ * RPB)     // 18560 = 145 * 128
#define EPS_   1e-4f
#define KC_    100            // k-chunk for final_partial (4000 = 40*100)
#define NKC    40
#define BT_    8              // batch-tile for final_partial (128 = 16*8)

typedef __bf16 bf16;
typedef bf16 bf16x8 __attribute__((ext_vector_type(8)));
typedef bf16 bf16x4 __attribute__((ext_vector_type(4)));
typedef float f32x4 __attribute__((ext_vector_type(4)));

#define MFMA(a, b, c) __builtin_amdgcn_mfma_f32_16x16x32_bf16(a, b, c, 0, 0, 0)

__device__ __forceinline__ void gload_lds16(const void* g, void* l) {
  __builtin_amdgcn_global_load_lds(
      (const __attribute__((address_space(1))) unsigned int*)g,
      (__attribute__((address_space(3))) unsigned int*)l, 16, 0, 0);
}

// ---------------------------------------------------------------------------
// Prologue, 4 block ranges (all depend only on kernel inputs):
//  [0,128)        : per-batch top-K (stable, lower-index-wins) -> rowidx
//  [128,1052)     : f32->bf16 convert of 4 weights + proto_local
//  [1052,2064)    : prototype norms, f32-exact (pnl from proto_l, png from
//                   proto_g); pnl rows >= P_ set to 0
//  [2064,2846)    : prep_wt  wT2[c][k] = {0.3*lwg | 0.7*lw}
// ---------------------------------------------------------------------------
#define SEG1 73728     // 384*768/4
#define SEG2 36864     // 384*384/4
#define SEG3 18432     // 192*384/4
#define SEG4 9216      // 192*192/4
#define SEG5 98304     // PPAD*C_/4
#define CVT_TOT (SEG1 + SEG2 + SEG3 + SEG4 + SEG5)  // 236544 = 924*256
#define CVT_BLKS   (CVT_TOT / 256)                  // 924
#define PN_ROWS    (PPAD + P_)                      // 4048
#define PN_BLKS    (PN_ROWS / 4)                    // 1012
#define PREP_Q     (NC_ * 4000 / 4)                 // 200000 float4s
#define PREP_BLKS  ((PREP_Q + 255) / 256)           // 782
#define PRO_B1     (B_)
#define PRO_B2     (PRO_B1 + CVT_BLKS)
#define PRO_B3     (PRO_B2 + PN_BLKS)
#define PRO_TOT    (PRO_B3 + PREP_BLKS)

__global__ __launch_bounds__(256) void prologue(
    const float* __restrict__ attn, int* __restrict__ rowidx,
    const float* __restrict__ w1, const float* __restrict__ w2,
    const float* __restrict__ w3, const float* __restrict__ w4,
    const float* __restrict__ pl, const float* __restrict__ pg,
    const float* __restrict__ lwg, const float* __restrict__ lw,
    bf16* __restrict__ w1b, bf16* __restrict__ w2b,
    bf16* __restrict__ w3b, bf16* __restrict__ w4b,
    bf16* __restrict__ plb, float* __restrict__ pnl,
    float* __restrict__ png, float* __restrict__ wT2) {
  if (blockIdx.x < PRO_B1) {
    __shared__ float av[N_TOK];
    __shared__ int   flag[N_TOK];
    int b = blockIdx.x, t = threadIdx.x;
    if (t < N_TOK) av[t] = attn[b * N_TOK + t];
    __syncthreads();
    if (t < N_TOK) {
      float v = av[t];
      int rank = 0;
      for (int j = 0; j < N_TOK; ++j) {
        float u = av[j];
        rank += (u > v || (u == v && j < t)) ? 1 : 0;
      }
      flag[t] = (rank < K_SEL) ? 1 : 0;
    }
    __syncthreads();
    if (t == 0) rowidx[b * RPB] = b * (N_TOK + 1);
    if (t < N_TOK && flag[t]) {
      int pos = 0;
      for (int j = 0; j < t; ++j) pos += flag[j];
      rowidx[b * RPB + 1 + pos] = b * (N_TOK + 1) + 1 + t;
    }
    return;
  }
  if (blockIdx.x < PRO_B2) {
    int i4 = (blockIdx.x - PRO_B1) * 256 + threadIdx.x;
    const float* s; bf16* d; int nv; int base;
    if (i4 < SEG1)                       { s = w1; d = w1b; nv = 384 * 768; base = i4; }
    else if (i4 < SEG1 + SEG2)           { s = w2; d = w2b; nv = 384 * 384; base = i4 - SEG1; }
    else if (i4 < SEG1 + SEG2 + SEG3)    { s = w3; d = w3b; nv = 192 * 384; base = i4 - (SEG1 + SEG2); }
    else if (i4 < SEG1 + SEG2 + SEG3 + SEG4) { s = w4; d = w4b; nv = 192 * 192; base = i4 - (SEG1 + SEG2 + SEG3); }
    else                                 { s = pl; d = plb; nv = P_ * C_; base = i4 - (SEG1 + SEG2 + SEG3 + SEG4); }
    int i = base * 4;
    bf16x4 o;
#pragma unroll
    for (int j = 0; j < 4; ++j)
      o[j] = (i + j < nv) ? (bf16)s[i + j] : (bf16)0.f;
    *reinterpret_cast<bf16x4*>(d + i) = o;
    return;
  }
  if (blockIdx.x < PRO_B3) {
    int m = (blockIdx.x - PRO_B2) * 4 + (threadIdx.x >> 6);
    int lane = threadIdx.x & 63;
    float s = 0.f;
    if (m < PPAD) {
      if (m < P_) {
        const float* f = pl + (size_t)m * C_;
#pragma unroll
        for (int k = 0; k < 3; ++k) { float v = f[lane + k * 64]; s += v * v; }
      }
    } else {
      const float* f = pg + (size_t)(m - PPAD) * C_;
#pragma unroll
      for (int k = 0; k < 3; ++k) { float v = f[lane + k * 64]; s += v * v; }
    }
    for (int o = 32; o > 0; o >>= 1) s += __shfl_down(s, o, 64);
    if (lane == 0) {
      if (m < PPAD) pnl[m] = s;
      else png[m - PPAD] = s;
    }
    return;
  }
  int i4 = (blockIdx.x - PRO_B3) * 256 + threadIdx.x;
  if (i4 >= PREP_Q) return;
  int c = i4 / 1000, k4 = i4 - c * 1000;   // 1000 float4s per c-row
  float4 v;
  if (k4 < 500) {
    v = *reinterpret_cast<const float4*>(lwg + (size_t)c * 2000 + k4 * 4);
    v.x *= 0.3f; v.y *= 0.3f; v.z *= 0.3f; v.w *= 0.3f;
  } else {
    v = *reinterpret_cast<const float4*>(lw + (size_t)c * 2000 + (k4 - 500) * 4);
    v.x *= 0.7f; v.y *= 0.7f; v.z *= 0.7f; v.w *= 0.7f;
  }
  *reinterpret_cast<float4*>(wT2 + (size_t)i4 * 4) = v;
}

// ---------------------------------------------------------------------------
// Gather selected token rows from x_tokens, convert f32 -> bf16.
// ---------------------------------------------------------------------------
__global__ __launch_bounds__(192) void gather_cvt(const float* __restrict__ x,
                                                  const int* __restrict__ rowidx,
                                                  bf16* __restrict__ A0) {
  int row = blockIdx.x;
  int src = rowidx[row];
  int t = threadIdx.x;
  float4 v = *reinterpret_cast<const float4*>(x + (size_t)src * D_IN + t * 4);
  bf16x4 o;
  o[0] = (bf16)v.x; o[1] = (bf16)v.y; o[2] = (bf16)v.z; o[3] = (bf16)v.w;
  *reinterpret_cast<bf16x4*>(A0 + (size_t)row * D_IN + t * 4) = o;
}

// ---------------------------------------------------------------------------
// bf16 MFMA GEMM with 2-phase double-buffered prefetch (T3-minimum):
// stage(t+1) issued BEFORE compute(t); one __syncthreads per K-step.
// BM=128, BN templated, BK=64. 4 waves (2x2), wave tile 64 x (BN/2).
// LDS XOR-swizzled (16B granule) with pre-swizzled global source (rule #21).
// ---------------------------------------------------------------------------
template <int ACT, int BN>
__global__ __launch_bounds__(256, 2) void gemm_bf16(
    const bf16* __restrict__ A, const bf16* __restrict__ W,
    const float* __restrict__ bias, bf16* __restrict__ out, int N, int Kd) {
  constexpr int NF = BN / 32;            // N-frags per wave
  __shared__ __align__(16) bf16 As[2][128 * 64];
  __shared__ __align__(16) bf16 Bs[2][BN * 64];
  const int bm = blockIdx.x * 128, bn = blockIdx.y * BN;
  const int tid = threadIdx.x;
  const int lane = tid & 63, wid = tid >> 6;
  const int wm = (wid >> 1) * 64, wn = (wid & 1) * (BN / 2);
  const int l15 = lane & 15, lhi = lane >> 4;

  auto stage = [&](int buf, int k0) {
#pragma unroll
    for (int i = 0; i < 4; ++i) {
      int o = i * 256 + tid;
      int r = o >> 3, cb = o & 7;
      int gc = (cb ^ (r & 7)) * 8;
      gload_lds16(A + (size_t)(bm + r) * Kd + k0 + gc, (char*)As[buf] + o * 16);
    }
#pragma unroll
    for (int i = 0; i < NF; ++i) {
      int o = i * 256 + tid;
      int r = o >> 3, cb = o & 7;
      int gc = (cb ^ (r & 7)) * 8;
      gload_lds16(W + (size_t)(bn + r) * Kd + k0 + gc, (char*)Bs[buf] + o * 16);
    }
  };

  f32x4 acc[4][NF] = {};
  const int NT = Kd >> 6;
  stage(0, 0);
  __syncthreads();                         // drain stage(0)
  for (int kt = 0; kt < NT; ++kt) {
    if (kt + 1 < NT) stage((kt + 1) & 1, (kt + 1) * 64);
    const char* Ab = (const char*)As[kt & 1];
    const char* Bb = (const char*)Bs[kt & 1];
#pragma unroll
    for (int kk = 0; kk < 2; ++kk) {
      bf16x8 bfr[NF];
#pragma unroll
      for (int nf = 0; nf < NF; ++nf) {
        int rr = wn + nf * 16 + l15;
        int c = kk * 4 + lhi;
        bfr[nf] = *reinterpret_cast<const bf16x8*>(Bb + (rr * 8 + (c ^ (rr & 7))) * 16);
      }
#pragma unroll
      for (int mf = 0; mf < 4; ++mf) {
        int rr = wm + mf * 16 + l15;
        int c = kk * 4 + lhi;
        bf16x8 afr = *reinterpret_cast<const bf16x8*>(Ab + (rr * 8 + (c ^ (rr & 7))) * 16);
#pragma unroll
        for (int nf = 0; nf < NF; ++nf)
          acc[mf][nf] = MFMA(afr, bfr[nf], acc[mf][nf]);
      }
    }
    __syncthreads();                       // drains stage(kt+1); guards reuse
  }
#pragma unroll
  for (int mf = 0; mf < 4; ++mf)
#pragma unroll
    for (int nf = 0; nf < NF; ++nf) {
      int col = bn + wn + nf * 16 + l15;
      float bv = bias[col];
#pragma unroll
      for (int q = 0; q < 4; ++q) {
        int row = bm + wm + mf * 16 + lhi * 4 + q;
        float v = acc[mf][nf][q] + bv;
        v = (ACT == 0) ? fmaxf(v, 0.f) : 1.f / (1.f + expf(-v));
        out[(size_t)row * N + col] = (bf16)v;
      }
    }
}

// ---------------------------------------------------------------------------
// fnorm-only mid kernel (pnorms/prep moved to prologue).
// ---------------------------------------------------------------------------
__global__ __launch_bounds__(256) void fnorm_k(const bf16* __restrict__ F,
                                               float* __restrict__ fnorm) {
  int m = blockIdx.x * 4 + (threadIdx.x >> 6);
  int lane = threadIdx.x & 63;
  const bf16* f = F + (size_t)m * C_;
  float s = 0.f;
#pragma unroll
  for (int k = 0; k < 3; ++k) { float v = (float)f[lane + k * 64]; s += v * v; }
  for (int o = 32; o > 0; o >>= 1) s += __shfl_down(s, o, 64);
  if (lane == 0) fnorm[m] = s;
}

// ---------------------------------------------------------------------------
// Fused distances, one dispatch:
// blocks [0, 2048):  image distances, 144 token rows (9 m-frags), 2-phase
//                    dbuf F-staging; P-OPERAND IN REGISTERS (12 bf16x8/lane,
//                    loaded once from L2 at block start — bit-identical
//                    values/order vs the old LDS path, swizzle cancels).
//                    XCD-chunked block swizzle for per-XCD L2 reuse.
// blocks [2048, 3048): cls distances vs proto_global (1 thread per (b,p)).
// ---------------------------------------------------------------------------
#define NIMG_BLKS (PPAD / 128 * B_)     // 2048
#define NCLS_BLKS (B_ * P_ / 256)       // 1000
#define FG_ (K_SEL * 8)                 // 1152 F granules per K-step

__global__ __launch_bounds__(256, 2) void dist_fused(
    const bf16* __restrict__ F, const bf16* __restrict__ P,
    const float* __restrict__ fnorm, const float* __restrict__ pnl,
    const float* __restrict__ proto_g, const float* __restrict__ png,
    float* __restrict__ act_l, float* __restrict__ act_g) {
  __shared__ __align__(16) bf16 Fs[2][K_SEL * 64];   // 36864 B
  __shared__ float fn[K_SEL];
  const int tid = threadIdx.x;
  if (blockIdx.x >= NIMG_BLKS) {
    // ---- cls-distance branch
    int i = (blockIdx.x - NIMG_BLKS) * 256 + tid;  // < 128*2000 exactly
    int b = i / P_, p = i - b * P_;
    const bf16* f = F + (size_t)(b * RPB) * C_;
    const float* pr = proto_g + (size_t)p * C_;
    float dot = 0.f;
    for (int k = 0; k < C_; k += 8) {
      bf16x8 fv = *reinterpret_cast<const bf16x8*>(f + k);
      float4 p0 = *reinterpret_cast<const float4*>(pr + k);
      float4 p1 = *reinterpret_cast<const float4*>(pr + k + 4);
      dot += (float)fv[0] * p0.x + (float)fv[1] * p0.y + (float)fv[2] * p0.z +
             (float)fv[3] * p0.w + (float)fv[4] * p1.x + (float)fv[5] * p1.y +
             (float)fv[6] * p1.z + (float)fv[7] * p1.w;
    }
    float d = fmaxf(fnorm[b * RPB] - 2.f * dot + png[p], 0.f);
    act_g[i] = logf((d + 1.f) / (d + EPS_));
    return;
  }
  // ---- image-distance branch (2-phase dbuf F, reg-P, XCD-chunk swizzle)
  const int lb = (blockIdx.x & 7) * (NIMG_BLKS / 8) + (blockIdx.x >> 3);
  const int b = lb >> 4;
  const int p0 = (lb & 15) * 128;
  const int lane = tid & 63, wid = tid >> 6;
  const int wn = wid * 32;
  const int l15 = lane & 15, lhi = lane >> 4;
  const bf16* Fbase = F + (size_t)(b * RPB + 1) * C_;   // selected rows only

  // P fragments in registers: [kt][kk][nf]; same values & MFMA order as the
  // former LDS-staged path (XOR swizzle cancels on read) => bitwise-identical.
  bf16x8 bfr[3][2][2];
#pragma unroll
  for (int kt = 0; kt < 3; ++kt)
#pragma unroll
    for (int kk = 0; kk < 2; ++kk)
#pragma unroll
      for (int nf = 0; nf < 2; ++nf) {
        int rr = wn + nf * 16 + l15;
        int c = kk * 4 + lhi;
        bfr[kt][kk][nf] = *reinterpret_cast<const bf16x8*>(
            P + (size_t)(p0 + rr) * C_ + kt * 64 + c * 8);
      }

  auto stage = [&](int buf, int k0) {
#pragma unroll
    for (int i = 0; i < 5; ++i) {
      int o = i * 256 + tid;
      if (o < FG_) {
        int r = o >> 3, cb = o & 7;
        int gc = (cb ^ (r & 7)) * 8;
        gload_lds16(Fbase + (size_t)r * C_ + k0 + gc, (char*)Fs[buf] + o * 16);
      }
    }
  };

  if (tid < K_SEL) fn[tid] = fnorm[b * RPB + 1 + tid];
  f32x4 acc[9][2] = {};
  stage(0, 0);
  __syncthreads();
#pragma unroll
  for (int kt = 0; kt < 3; ++kt) {
    if (kt + 1 < 3) stage((kt + 1) & 1, (kt + 1) * 64);
    const char* Fbuf = (const char*)Fs[kt & 1];
#pragma unroll
    for (int kk = 0; kk < 2; ++kk) {
#pragma unroll
      for (int mf = 0; mf < 9; ++mf) {
        int rr = mf * 16 + l15;
        int c = kk * 4 + lhi;
        bf16x8 afr = *reinterpret_cast<const bf16x8*>(
            Fbuf + (rr * 8 + (c ^ (rr & 7))) * 16);
        acc[mf][0] = MFMA(afr, bfr[kt][kk][0], acc[mf][0]);
        acc[mf][1] = MFMA(afr, bfr[kt][kk][1], acc[mf][1]);
      }
    }
    __syncthreads();
  }
#pragma unroll
  for (int nf = 0; nf < 2; ++nf) {
    float mn = 3.4e38f;
#pragma unroll
    for (int mf = 0; mf < 9; ++mf)
#pragma unroll
      for (int q = 0; q < 4; ++q) {
        int row = mf * 16 + lhi * 4 + q;
        mn = fminf(mn, fn[row] - 2.f * acc[mf][nf][q]);
      }
    mn = fminf(mn, __shfl_xor(mn, 16, 64));
    mn = fminf(mn, __shfl_xor(mn, 32, 64));
    int p = p0 + wn + nf * 16 + l15;
    if (lhi == 0 && p < P_) {
      float d = fmaxf(mn + pnl[p], 0.f);
      act_l[(size_t)b * P_ + p] = logf((d + 1.f) / (d + EPS_));
    }
  }
}

// ---------------------------------------------------------------------------
// final_partial: part[kc][b][c] = sum_{k in chunk} act[b][k] * wT2[c][k]
// final_reduce:  out[b][c] = sum_kc part[kc][b][c]
// ---------------------------------------------------------------------------
__global__ __launch_bounds__(256) void final_partial(
    const float* __restrict__ actg, const float* __restrict__ actl,
    const float* __restrict__ wT2, float* __restrict__ part) {
  __shared__ __align__(16) float sa[KC_][BT_];
  const int kc = blockIdx.x;   // 0..39
  const int bt = blockIdx.y;   // 0..15
  const int t = threadIdx.x;
  const int b0 = bt * BT_;
  const int kg0 = kc * KC_;
  const float* act = (kg0 < 2000) ? actg : actl;
  const int koff = (kg0 < 2000) ? kg0 : kg0 - 2000;
  for (int i = t; i < KC_ * BT_; i += 256) {
    int b = i / KC_;
    int k = i - b * KC_;
    sa[k][b] = act[(size_t)(b0 + b) * P_ + koff + k];
  }
  __syncthreads();
  const int c = t;
  if (c >= NC_) return;
  float acc[BT_] = {};
  const float4* w4p = reinterpret_cast<const float4*>(wT2 + (size_t)c * 4000 + kg0);
#pragma unroll 5
  for (int k4 = 0; k4 < KC_ / 4; ++k4) {
    float4 w4 = w4p[k4];
    float wv[4] = {w4.x, w4.y, w4.z, w4.w};
#pragma unroll
    for (int j = 0; j < 4; ++j) {
      float w = wv[j];
      const float4* s4 = reinterpret_cast<const float4*>(&sa[k4 * 4 + j][0]);
      float4 a0 = s4[0], a1 = s4[1];
      acc[0] += w * a0.x; acc[1] += w * a0.y; acc[2] += w * a0.z; acc[3] += w * a0.w;
      acc[4] += w * a1.x; acc[5] += w * a1.y; acc[6] += w * a1.z; acc[7] += w * a1.w;
    }
  }
#pragma unroll
  for (int b = 0; b < BT_; ++b)
    part[((size_t)kc * B_ + b0 + b) * NC_ + c] = acc[b];
}

__global__ __launch_bounds__(256) void final_reduce(const float* __restrict__ part,
                                                    float* __restrict__ out) {
  int i = blockIdx.x * 256 + threadIdx.x;
  if (i >= B_ * NC_) return;
  float s = 0.f;
#pragma unroll 8
  for (int kc = 0; kc < NKC; ++kc) s += part[(size_t)kc * (B_ * NC_) + i];
  out[i] = s;
}

// ---------------------------------------------------------------------------
extern "C" void kernel_launch(void* const* d_in, const int* in_sizes, int n_in,
                              void* d_out, int out_size, void* d_ws, size_t ws_size,
                              hipStream_t stream) {
  const float* x_tokens = (const float*)d_in[0];
  const float* attn     = (const float*)d_in[1];
  const float* w1 = (const float*)d_in[2];
  const float* b1 = (const float*)d_in[3];
  const float* w2 = (const float*)d_in[4];
  const float* b2 = (const float*)d_in[5];
  const float* w3 = (const float*)d_in[6];
  const float* b3 = (const float*)d_in[7];
  const float* w4 = (const float*)d_in[8];
  const float* b4 = (const float*)d_in[9];
  const float* proto_l = (const float*)d_in[10];
  const float* proto_g = (const float*)d_in[11];
  const float* last_w  = (const float*)d_in[12];
  const float* last_wg = (const float*)d_in[13];
  float* out = (float*)d_out;

  char* wsb = (char*)d_ws;
  auto alloc = [&](size_t bytes) {
    char* p = wsb;
    wsb += (bytes + 255) & ~(size_t)255;
    return p;
  };
  // A0 region (28.5 MB) is dead after gemm1; bufB, wT2, part alias into it.
  bf16* A0   = (bf16*)alloc((size_t)M_PAD * D_IN * sizeof(bf16));   // 28.5 MB
  bf16* bufA = (bf16*)alloc((size_t)M_PAD * 384 * sizeof(bf16));    // 14.3 MB
  bf16* w1b = (bf16*)alloc((size_t)384 * 768 * sizeof(bf16));
  bf16* w2b = (bf16*)alloc((size_t)384 * 384 * sizeof(bf16));
  bf16* w3b = (bf16*)alloc((size_t)192 * 384 * sizeof(bf16));
  bf16* w4b = (bf16*)alloc((size_t)192 * 192 * sizeof(bf16));
  bf16* plb = (bf16*)alloc((size_t)PPAD * C_ * sizeof(bf16));
  int*   rowidx = (int*)  alloc((size_t)M_PAD * sizeof(int));
  float* fnorm  = (float*)alloc((size_t)M_PAD * sizeof(float));
  float* pnl    = (float*)alloc((size_t)PPAD * sizeof(float));
  float* png    = (float*)alloc((size_t)P_ * sizeof(float));
  float* actg   = (float*)alloc((size_t)B_ * P_ * sizeof(float));
  float* actl   = (float*)alloc((size_t)B_ * P_ * sizeof(float));
  // wT2 is written in prologue (before gemm1 finishes) so it canNOT alias A0:
  float* wT2    = (float*)alloc((size_t)NC_ * 4000 * sizeof(float)); // 3.2 MB

  // aliases inside A0's 28.5 MB (A0 dead after gemm1; offsets checked):
  bf16*  bufB = A0;                                        // 14.3 MB used
  float* part = (float*)((char*)A0 + 19 * 1024 * 1024);    // 4.1 MB (19..23.1 < 28.5)

  bf16* H1 = bufA;   // [M_PAD][384]
  bf16* H2 = bufB;   // [M_PAD][384]  overwrites dead A0
  bf16* H3 = bufA;   // [M_PAD][192]  (H1 dead after gemm2)
  bf16* Fb = bufB;   // [M_PAD][192]  (H2 dead after gemm3; 7.2 MB < 14.3)

  prologue<<<PRO_TOT, 256, 0, stream>>>(
      attn, rowidx, w1, w2, w3, w4, proto_l, proto_g, last_wg, last_w,
      w1b, w2b, w3b, w4b, plb, pnl, png, wT2);

  gather_cvt<<<M_PAD, 192, 0, stream>>>(x_tokens, rowidx, A0);

  gemm_bf16<0, 128><<<dim3(M_PAD / 128, 384 / 128), 256, 0, stream>>>(
      A0, w1b, b1, H1, 384, 768);
  gemm_bf16<0, 128><<<dim3(M_PAD / 128, 384 / 128), 256, 0, stream>>>(
      H1, w2b, b2, H2, 384, 384);
  gemm_bf16<0, 64><<<dim3(M_PAD / 128, 192 / 64), 256, 0, stream>>>(
      H2, w3b, b3, H3, 192, 384);
  gemm_bf16<1, 64><<<dim3(M_PAD / 128, 192 / 64), 256, 0, stream>>>(
      H3, w4b, b4, Fb, 192, 192);

  fnorm_k<<<M_PAD / 4, 256, 0, stream>>>(Fb, fnorm);

  dist_fused<<<NIMG_BLKS + NCLS_BLKS, 256, 0, stream>>>(
      Fb, plb, fnorm, pnl, proto_g, png, actl, actg);

  final_partial<<<dim3(NKC, B_ / BT_), 256, 0, stream>>>(actg, actl, wT2, part);
  final_reduce<<<(B_ * NC_ + 255) / 256, 256, 0, stream>>>(part, out);
}

// Round 16
// 147.201 us; speedup vs baseline: 1.0247x; 1.0247x over previous
//
#include <hip/hip_runtime.h>
#include <cstdint>
#include <cstddef>

#define B_     128
#define N_TOK  196
#define D_IN   768
#define K_SEL  144
#define P_     2000
#define PPAD   2048
#define C_     192
#define NC_    200
#define RPB    145            // rows per batch: 1 cls + 144 selected (no pad)
#define M_PAD  (B_ * RPB)     // 18560 = 145 * 128
#define EPS_   1e-4f
#define KC_    100            // k-chunk for final_partial (4000 = 40*100)
#define NKC    40
#define BT_    8              // batch-tile for final_partial (128 = 16*8)

typedef __bf16 bf16;
typedef bf16 bf16x8 __attribute__((ext_vector_type(8)));
typedef bf16 bf16x4 __attribute__((ext_vector_type(4)));
typedef float f32x4 __attribute__((ext_vector_type(4)));

#define MFMA(a, b, c) __builtin_amdgcn_mfma_f32_16x16x32_bf16(a, b, c, 0, 0, 0)

__device__ __forceinline__ void gload_lds16(const void* g, void* l) {
  __builtin_amdgcn_global_load_lds(
      (const __attribute__((address_space(1))) unsigned int*)g,
      (__attribute__((address_space(3))) unsigned int*)l, 16, 0, 0);
}

// ---------------------------------------------------------------------------
// Prologue, 4 block ranges (all depend only on kernel inputs):
//  [0,128)        : per-batch top-K (stable, lower-index-wins) -> rowidx
//  [128,1052)     : f32->bf16 convert of 4 weights + proto_local
//  [1052,2064)    : prototype norms, f32-exact; pnl rows >= P_ = 0
//  [2064,2846)    : prep_wt  wT2[c][k] = {0.3*lwg | 0.7*lw}
// ---------------------------------------------------------------------------
#define SEG1 73728     // 384*768/4
#define SEG2 36864     // 384*384/4
#define SEG3 18432     // 192*384/4
#define SEG4 9216      // 192*192/4
#define SEG5 98304     // PPAD*C_/4
#define CVT_TOT (SEG1 + SEG2 + SEG3 + SEG4 + SEG5)  // 236544 = 924*256
#define CVT_BLKS   (CVT_TOT / 256)                  // 924
#define PN_ROWS    (PPAD + P_)                      // 4048
#define PN_BLKS    (PN_ROWS / 4)                    // 1012
#define PREP_Q     (NC_ * 4000 / 4)                 // 200000 float4s
#define PREP_BLKS  ((PREP_Q + 255) / 256)           // 782
#define PRO_B1     (B_)
#define PRO_B2     (PRO_B1 + CVT_BLKS)
#define PRO_B3     (PRO_B2 + PN_BLKS)
#define PRO_TOT    (PRO_B3 + PREP_BLKS)

__global__ __launch_bounds__(256) void prologue(
    const float* __restrict__ attn, int* __restrict__ rowidx,
    const float* __restrict__ w1, const float* __restrict__ w2,
    const float* __restrict__ w3, const float* __restrict__ w4,
    const float* __restrict__ pl, const float* __restrict__ pg,
    const float* __restrict__ lwg, const float* __restrict__ lw,
    bf16* __restrict__ w1b, bf16* __restrict__ w2b,
    bf16* __restrict__ w3b, bf16* __restrict__ w4b,
    bf16* __restrict__ plb, float* __restrict__ pnl,
    float* __restrict__ png, float* __restrict__ wT2) {
  if (blockIdx.x < PRO_B1) {
    __shared__ float av[N_TOK];
    __shared__ int   flag[N_TOK];
    int b = blockIdx.x, t = threadIdx.x;
    if (t < N_TOK) av[t] = attn[b * N_TOK + t];
    __syncthreads();
    if (t < N_TOK) {
      float v = av[t];
      int rank = 0;
      for (int j = 0; j < N_TOK; ++j) {
        float u = av[j];
        rank += (u > v || (u == v && j < t)) ? 1 : 0;
      }
      flag[t] = (rank < K_SEL) ? 1 : 0;
    }
    __syncthreads();
    if (t == 0) rowidx[b * RPB] = b * (N_TOK + 1);
    if (t < N_TOK && flag[t]) {
      int pos = 0;
      for (int j = 0; j < t; ++j) pos += flag[j];
      rowidx[b * RPB + 1 + pos] = b * (N_TOK + 1) + 1 + t;
    }
    return;
  }
  if (blockIdx.x < PRO_B2) {
    int i4 = (blockIdx.x - PRO_B1) * 256 + threadIdx.x;
    const float* s; bf16* d; int nv; int base;
    if (i4 < SEG1)                       { s = w1; d = w1b; nv = 384 * 768; base = i4; }
    else if (i4 < SEG1 + SEG2)           { s = w2; d = w2b; nv = 384 * 384; base = i4 - SEG1; }
    else if (i4 < SEG1 + SEG2 + SEG3)    { s = w3; d = w3b; nv = 192 * 384; base = i4 - (SEG1 + SEG2); }
    else if (i4 < SEG1 + SEG2 + SEG3 + SEG4) { s = w4; d = w4b; nv = 192 * 192; base = i4 - (SEG1 + SEG2 + SEG3); }
    else                                 { s = pl; d = plb; nv = P_ * C_; base = i4 - (SEG1 + SEG2 + SEG3 + SEG4); }
    int i = base * 4;
    bf16x4 o;
#pragma unroll
    for (int j = 0; j < 4; ++j)
      o[j] = (i + j < nv) ? (bf16)s[i + j] : (bf16)0.f;
    *reinterpret_cast<bf16x4*>(d + i) = o;
    return;
  }
  if (blockIdx.x < PRO_B3) {
    int m = (blockIdx.x - PRO_B2) * 4 + (threadIdx.x >> 6);
    int lane = threadIdx.x & 63;
    float s = 0.f;
    if (m < PPAD) {
      if (m < P_) {
        const float* f = pl + (size_t)m * C_;
#pragma unroll
        for (int k = 0; k < 3; ++k) { float v = f[lane + k * 64]; s += v * v; }
      }
    } else {
      const float* f = pg + (size_t)(m - PPAD) * C_;
#pragma unroll
      for (int k = 0; k < 3; ++k) { float v = f[lane + k * 64]; s += v * v; }
    }
    for (int o = 32; o > 0; o >>= 1) s += __shfl_down(s, o, 64);
    if (lane == 0) {
      if (m < PPAD) pnl[m] = s;
      else png[m - PPAD] = s;
    }
    return;
  }
  int i4 = (blockIdx.x - PRO_B3) * 256 + threadIdx.x;
  if (i4 >= PREP_Q) return;
  int c = i4 / 1000, k4 = i4 - c * 1000;   // 1000 float4s per c-row
  float4 v;
  if (k4 < 500) {
    v = *reinterpret_cast<const float4*>(lwg + (size_t)c * 2000 + k4 * 4);
    v.x *= 0.3f; v.y *= 0.3f; v.z *= 0.3f; v.w *= 0.3f;
  } else {
    v = *reinterpret_cast<const float4*>(lw + (size_t)c * 2000 + (k4 - 500) * 4);
    v.x *= 0.7f; v.y *= 0.7f; v.z *= 0.7f; v.w *= 0.7f;
  }
  *reinterpret_cast<float4*>(wT2 + (size_t)i4 * 4) = v;
}

// ---------------------------------------------------------------------------
// Gather selected token rows from x_tokens, convert f32 -> bf16.
// ---------------------------------------------------------------------------
__global__ __launch_bounds__(192) void gather_cvt(const float* __restrict__ x,
                                                  const int* __restrict__ rowidx,
                                                  bf16* __restrict__ A0) {
  int row = blockIdx.x;
  int src = rowidx[row];
  int t = threadIdx.x;
  float4 v = *reinterpret_cast<const float4*>(x + (size_t)src * D_IN + t * 4);
  bf16x4 o;
  o[0] = (bf16)v.x; o[1] = (bf16)v.y; o[2] = (bf16)v.z; o[3] = (bf16)v.w;
  *reinterpret_cast<bf16x4*>(A0 + (size_t)row * D_IN + t * 4) = o;
}

// ---------------------------------------------------------------------------
// bf16 MFMA GEMM with 2-phase double-buffered prefetch (T3-minimum).
// ---------------------------------------------------------------------------
template <int ACT, int BN>
__global__ __launch_bounds__(256, 2) void gemm_bf16(
    const bf16* __restrict__ A, const bf16* __restrict__ W,
    const float* __restrict__ bias, bf16* __restrict__ out, int N, int Kd) {
  constexpr int NF = BN / 32;            // N-frags per wave
  __shared__ __align__(16) bf16 As[2][128 * 64];
  __shared__ __align__(16) bf16 Bs[2][BN * 64];
  const int bm = blockIdx.x * 128, bn = blockIdx.y * BN;
  const int tid = threadIdx.x;
  const int lane = tid & 63, wid = tid >> 6;
  const int wm = (wid >> 1) * 64, wn = (wid & 1) * (BN / 2);
  const int l15 = lane & 15, lhi = lane >> 4;

  auto stage = [&](int buf, int k0) {
#pragma unroll
    for (int i = 0; i < 4; ++i) {
      int o = i * 256 + tid;
      int r = o >> 3, cb = o & 7;
      int gc = (cb ^ (r & 7)) * 8;
      gload_lds16(A + (size_t)(bm + r) * Kd + k0 + gc, (char*)As[buf] + o * 16);
    }
#pragma unroll
    for (int i = 0; i < NF; ++i) {
      int o = i * 256 + tid;
      int r = o >> 3, cb = o & 7;
      int gc = (cb ^ (r & 7)) * 8;
      gload_lds16(W + (size_t)(bn + r) * Kd + k0 + gc, (char*)Bs[buf] + o * 16);
    }
  };

  f32x4 acc[4][NF] = {};
  const int NT = Kd >> 6;
  stage(0, 0);
  __syncthreads();                         // drain stage(0)
  for (int kt = 0; kt < NT; ++kt) {
    if (kt + 1 < NT) stage((kt + 1) & 1, (kt + 1) * 64);
    const char* Ab = (const char*)As[kt & 1];
    const char* Bb = (const char*)Bs[kt & 1];
#pragma unroll
    for (int kk = 0; kk < 2; ++kk) {
      bf16x8 bfr[NF];
#pragma unroll
      for (int nf = 0; nf < NF; ++nf) {
        int rr = wn + nf * 16 + l15;
        int c = kk * 4 + lhi;
        bfr[nf] = *reinterpret_cast<const bf16x8*>(Bb + (rr * 8 + (c ^ (rr & 7))) * 16);
      }
#pragma unroll
      for (int mf = 0; mf < 4; ++mf) {
        int rr = wm + mf * 16 + l15;
        int c = kk * 4 + lhi;
        bf16x8 afr = *reinterpret_cast<const bf16x8*>(Ab + (rr * 8 + (c ^ (rr & 7))) * 16);
#pragma unroll
        for (int nf = 0; nf < NF; ++nf)
          acc[mf][nf] = MFMA(afr, bfr[nf], acc[mf][nf]);
      }
    }
    __syncthreads();                       // drains stage(kt+1); guards reuse
  }
#pragma unroll
  for (int mf = 0; mf < 4; ++mf)
#pragma unroll
    for (int nf = 0; nf < NF; ++nf) {
      int col = bn + wn + nf * 16 + l15;
      float bv = bias[col];
#pragma unroll
      for (int q = 0; q < 4; ++q) {
        int row = bm + wm + mf * 16 + lhi * 4 + q;
        float v = acc[mf][nf][q] + bv;
        v = (ACT == 0) ? fmaxf(v, 0.f) : 1.f / (1.f + expf(-v));
        out[(size_t)row * N + col] = (bf16)v;
      }
    }
}

// ---------------------------------------------------------------------------
// fnorm-only kernel (pnorms/prep moved to prologue).
// ---------------------------------------------------------------------------
__global__ __launch_bounds__(256) void fnorm_k(const bf16* __restrict__ F,
                                               float* __restrict__ fnorm) {
  int m = blockIdx.x * 4 + (threadIdx.x >> 6);
  int lane = threadIdx.x & 63;
  const bf16* f = F + (size_t)m * C_;
  float s = 0.f;
#pragma unroll
  for (int k = 0; k < 3; ++k) { float v = (float)f[lane + k * 64]; s += v * v; }
  for (int o = 32; o > 0; o >>= 1) s += __shfl_down(s, o, 64);
  if (lane == 0) fnorm[m] = s;
}

// ---------------------------------------------------------------------------
// Fused distances, one dispatch (r14-proven structure):
// blocks [0, 2048):  image distances, 144 token rows (9 m-frags), 2-phase
//                    dbuf MFMA (F and P both staged via global_load_lds) +
//                    min-over-tokens + log act. XCD-chunked block swizzle.
// blocks [2048, 3048): cls distances vs proto_global (1 thread per (b,p)).
// ---------------------------------------------------------------------------
#define NIMG_BLKS (PPAD / 128 * B_)     // 2048
#define NCLS_BLKS (B_ * P_ / 256)       // 1000
#define FG_ (K_SEL * 8)                 // 1152 F granules per K-step

__global__ __launch_bounds__(256, 2) void dist_fused(
    const bf16* __restrict__ F, const bf16* __restrict__ P,
    const float* __restrict__ fnorm, const float* __restrict__ pnl,
    const float* __restrict__ proto_g, const float* __restrict__ png,
    float* __restrict__ act_l, float* __restrict__ act_g) {
  __shared__ __align__(16) bf16 Fs[2][K_SEL * 64];
  __shared__ __align__(16) bf16 Ps[2][128 * 64];
  __shared__ float fn[K_SEL];
  const int tid = threadIdx.x;
  if (blockIdx.x >= NIMG_BLKS) {
    // ---- cls-distance branch
    int i = (blockIdx.x - NIMG_BLKS) * 256 + tid;  // < 128*2000 exactly
    int b = i / P_, p = i - b * P_;
    const bf16* f = F + (size_t)(b * RPB) * C_;
    const float* pr = proto_g + (size_t)p * C_;
    float dot = 0.f;
    for (int k = 0; k < C_; k += 8) {
      bf16x8 fv = *reinterpret_cast<const bf16x8*>(f + k);
      float4 p0 = *reinterpret_cast<const float4*>(pr + k);
      float4 p1 = *reinterpret_cast<const float4*>(pr + k + 4);
      dot += (float)fv[0] * p0.x + (float)fv[1] * p0.y + (float)fv[2] * p0.z +
             (float)fv[3] * p0.w + (float)fv[4] * p1.x + (float)fv[5] * p1.y +
             (float)fv[6] * p1.z + (float)fv[7] * p1.w;
    }
    float d = fmaxf(fnorm[b * RPB] - 2.f * dot + png[p], 0.f);
    act_g[i] = logf((d + 1.f) / (d + EPS_));
    return;
  }
  // ---- image-distance branch (2-phase dbuf, 144 rows, XCD-chunk swizzle)
  const int lb = (blockIdx.x & 7) * (NIMG_BLKS / 8) + (blockIdx.x >> 3);
  const int b = lb >> 4;
  const int p0 = (lb & 15) * 128;
  const int lane = tid & 63, wid = tid >> 6;
  const int wn = wid * 32;
  const int l15 = lane & 15, lhi = lane >> 4;
  const bf16* Fbase = F + (size_t)(b * RPB + 1) * C_;   // selected rows only

  auto stage = [&](int buf, int k0) {
#pragma unroll
    for (int i = 0; i < 5; ++i) {
      int o = i * 256 + tid;
      if (o < FG_) {
        int r = o >> 3, cb = o & 7;
        int gc = (cb ^ (r & 7)) * 8;
        gload_lds16(Fbase + (size_t)r * C_ + k0 + gc, (char*)Fs[buf] + o * 16);
      }
    }
#pragma unroll
    for (int i = 0; i < 4; ++i) {
      int o = i * 256 + tid;
      int r = o >> 3, cb = o & 7;
      int gc = (cb ^ (r & 7)) * 8;
      gload_lds16(P + (size_t)(p0 + r) * C_ + k0 + gc, (char*)Ps[buf] + o * 16);
    }
  };

  if (tid < K_SEL) fn[tid] = fnorm[b * RPB + 1 + tid];
  f32x4 acc[9][2] = {};
  stage(0, 0);
  __syncthreads();
  for (int kt = 0; kt < 3; ++kt) {
    if (kt + 1 < 3) stage((kt + 1) & 1, (kt + 1) * 64);
    const char* Fbuf = (const char*)Fs[kt & 1];
    const char* Pbuf = (const char*)Ps[kt & 1];
#pragma unroll
    for (int kk = 0; kk < 2; ++kk) {
      bf16x8 bfr[2];
#pragma unroll
      for (int nf = 0; nf < 2; ++nf) {
        int rr = wn + nf * 16 + l15;
        int c = kk * 4 + lhi;
        bfr[nf] = *reinterpret_cast<const bf16x8*>(Pbuf + (rr * 8 + (c ^ (rr & 7))) * 16);
      }
#pragma unroll
      for (int mf = 0; mf < 9; ++mf) {
        int rr = mf * 16 + l15;
        int c = kk * 4 + lhi;
        bf16x8 afr = *reinterpret_cast<const bf16x8*>(Fbuf + (rr * 8 + (c ^ (rr & 7))) * 16);
#pragma unroll
        for (int nf = 0; nf < 2; ++nf)
          acc[mf][nf] = MFMA(afr, bfr[nf], acc[mf][nf]);
      }
    }
    __syncthreads();
  }
#pragma unroll
  for (int nf = 0; nf < 2; ++nf) {
    float mn = 3.4e38f;
#pragma unroll
    for (int mf = 0; mf < 9; ++mf)
#pragma unroll
      for (int q = 0; q < 4; ++q) {
        int row = mf * 16 + lhi * 4 + q;
        mn = fminf(mn, fn[row] - 2.f * acc[mf][nf][q]);
      }
    mn = fminf(mn, __shfl_xor(mn, 16, 64));
    mn = fminf(mn, __shfl_xor(mn, 32, 64));
    int p = p0 + wn + nf * 16 + l15;
    if (lhi == 0 && p < P_) {
      float d = fmaxf(mn + pnl[p], 0.f);
      act_l[(size_t)b * P_ + p] = logf((d + 1.f) / (d + EPS_));
    }
  }
}

// ---------------------------------------------------------------------------
// final_partial: part[kc][b][c] = sum_{k in chunk} act[b][k] * wT2[c][k]
// final_reduce:  out[b][c] = sum_kc part[kc][b][c]
// ---------------------------------------------------------------------------
__global__ __launch_bounds__(256) void final_partial(
    const float* __restrict__ actg, const float* __restrict__ actl,
    const float* __restrict__ wT2, float* __restrict__ part) {
  __shared__ __align__(16) float sa[KC_][BT_];
  const int kc = blockIdx.x;   // 0..39
  const int bt = blockIdx.y;   // 0..15
  const int t = threadIdx.x;
  const int b0 = bt * BT_;
  const int kg0 = kc * KC_;
  const float* act = (kg0 < 2000) ? actg : actl;
  const int koff = (kg0 < 2000) ? kg0 : kg0 - 2000;
  for (int i = t; i < KC_ * BT_; i += 256) {
    int b = i / KC_;
    int k = i - b * KC_;
    sa[k][b] = act[(size_t)(b0 + b) * P_ + koff + k];
  }
  __syncthreads();
  const int c = t;
  if (c >= NC_) return;
  float acc[BT_] = {};
  const float4* w4p = reinterpret_cast<const float4*>(wT2 + (size_t)c * 4000 + kg0);
#pragma unroll 5
  for (int k4 = 0; k4 < KC_ / 4; ++k4) {
    float4 w4 = w4p[k4];
    float wv[4] = {w4.x, w4.y, w4.z, w4.w};
#pragma unroll
    for (int j = 0; j < 4; ++j) {
      float w = wv[j];
      const float4* s4 = reinterpret_cast<const float4*>(&sa[k4 * 4 + j][0]);
      float4 a0 = s4[0], a1 = s4[1];
      acc[0] += w * a0.x; acc[1] += w * a0.y; acc[2] += w * a0.z; acc[3] += w * a0.w;
      acc[4] += w * a1.x; acc[5] += w * a1.y; acc[6] += w * a1.z; acc[7] += w * a1.w;
    }
  }
#pragma unroll
  for (int b = 0; b < BT_; ++b)
    part[((size_t)kc * B_ + b0 + b) * NC_ + c] = acc[b];
}

__global__ __launch_bounds__(256) void final_reduce(const float* __restrict__ part,
                                                    float* __restrict__ out) {
  int i = blockIdx.x * 256 + threadIdx.x;
  if (i >= B_ * NC_) return;
  float s = 0.f;
#pragma unroll 8
  for (int kc = 0; kc < NKC; ++kc) s += part[(size_t)kc * (B_ * NC_) + i];
  out[i] = s;
}

// ---------------------------------------------------------------------------
extern "C" void kernel_launch(void* const* d_in, const int* in_sizes, int n_in,
                              void* d_out, int out_size, void* d_ws, size_t ws_size,
                              hipStream_t stream) {
  const float* x_tokens = (const float*)d_in[0];
  const float* attn     = (const float*)d_in[1];
  const float* w1 = (const float*)d_in[2];
  const float* b1 = (const float*)d_in[3];
  const float* w2 = (const float*)d_in[4];
  const float* b2 = (const float*)d_in[5];
  const float* w3 = (const float*)d_in[6];
  const float* b3 = (const float*)d_in[7];
  const float* w4 = (const float*)d_in[8];
  const float* b4 = (const float*)d_in[9];
  const float* proto_l = (const float*)d_in[10];
  const float* proto_g = (const float*)d_in[11];
  const float* last_w  = (const float*)d_in[12];
  const float* last_wg = (const float*)d_in[13];
  float* out = (float*)d_out;

  char* wsb = (char*)d_ws;
  auto alloc = [&](size_t bytes) {
    char* p = wsb;
    wsb += (bytes + 255) & ~(size_t)255;
    return p;
  };
  // A0 region (28.5 MB) is dead after gemm1; bufB, part alias into it.
  bf16* A0   = (bf16*)alloc((size_t)M_PAD * D_IN * sizeof(bf16));   // 28.5 MB
  bf16* bufA = (bf16*)alloc((size_t)M_PAD * 384 * sizeof(bf16));    // 14.3 MB
  bf16* w1b = (bf16*)alloc((size_t)384 * 768 * sizeof(bf16));
  bf16* w2b = (bf16*)alloc((size_t)384 * 384 * sizeof(bf16));
  bf16* w3b = (bf16*)alloc((size_t)192 * 384 * sizeof(bf16));
  bf16* w4b = (bf16*)alloc((size_t)192 * 192 * sizeof(bf16));
  bf16* plb = (bf16*)alloc((size_t)PPAD * C_ * sizeof(bf16));
  int*   rowidx = (int*)  alloc((size_t)M_PAD * sizeof(int));
  float* fnorm  = (float*)alloc((size_t)M_PAD * sizeof(float));
  float* pnl    = (float*)alloc((size_t)PPAD * sizeof(float));
  float* png    = (float*)alloc((size_t)P_ * sizeof(float));
  float* actg   = (float*)alloc((size_t)B_ * P_ * sizeof(float));
  float* actl   = (float*)alloc((size_t)B_ * P_ * sizeof(float));
  // wT2 is written in prologue (before gemm1 finishes) so it canNOT alias A0:
  float* wT2    = (float*)alloc((size_t)NC_ * 4000 * sizeof(float)); // 3.2 MB

  // aliases inside A0's 28.5 MB (A0 dead after gemm1; offsets checked):
  bf16*  bufB = A0;                                        // 14.3 MB used
  float* part = (float*)((char*)A0 + 19 * 1024 * 1024);    // 4.1 MB (19..23.1 < 28.5)

  bf16* H1 = bufA;   // [M_PAD][384]
  bf16* H2 = bufB;   // [M_PAD][384]  overwrites dead A0
  bf16* H3 = bufA;   // [M_PAD][192]  (H1 dead after gemm2)
  bf16* Fb = bufB;   // [M_PAD][192]  (H2 dead after gemm3; 7.2 MB < 14.3)

  prologue<<<PRO_TOT, 256, 0, stream>>>(
      attn, rowidx, w1, w2, w3, w4, proto_l, proto_g, last_wg, last_w,
      w1b, w2b, w3b, w4b, plb, pnl, png, wT2);

  gather_cvt<<<M_PAD, 192, 0, stream>>>(x_tokens, rowidx, A0);

  gemm_bf16<0, 128><<<dim3(M_PAD / 128, 384 / 128), 256, 0, stream>>>(
      A0, w1b, b1, H1, 384, 768);
  gemm_bf16<0, 128><<<dim3(M_PAD / 128, 384 / 128), 256, 0, stream>>>(
      H1, w2b, b2, H2, 384, 384);
  gemm_bf16<0, 64><<<dim3(M_PAD / 128, 192 / 64), 256, 0, stream>>>(
      H2, w3b, b3, H3, 192, 384);
  gemm_bf16<1, 64><<<dim3(M_PAD / 128, 192 / 64), 256, 0, stream>>>(
      H3, w4b, b4, Fb, 192, 192);

  fnorm_k<<<M_PAD / 4, 256, 0, stream>>>(Fb, fnorm);

  dist_fused<<<NIMG_BLKS + NCLS_BLKS, 256, 0, stream>>>(
      Fb, plb, fnorm, pnl, proto_g, png, actl, actg);

  final_partial<<<dim3(NKC, B_ / BT_), 256, 0, stream>>>(actg, actl, wT2, part);
  final_reduce<<<(B_ * NC_ + 255) / 256, 256, 0, stream>>>(part, out);
}